// Round 26
// baseline (294.146 us; speedup 1.0000x reference)
//
#include <hip/hip_runtime.h>
#include <hip/hip_bf16.h>
#include <math.h>
#include <stdint.h>

// B=8, P1=256 -> T=512 concat rows, C=1024, H=4096
#define TB_ 8
#define TT_ 512
#define TC_ 1024
#define WKV_NCH 32
#define WKV_L 16

typedef __attribute__((ext_vector_type(8))) short bf16x8;
typedef __attribute__((ext_vector_type(4))) short s16x4;
typedef __attribute__((ext_vector_type(4))) float f32x4;

__device__ __forceinline__ float b2f(short u) {
  union { unsigned int i; float f; } x;
  x.i = ((unsigned int)(unsigned short)u) << 16;
  return x.f;
}
__device__ __forceinline__ short f2b(float f) {
  __hip_bfloat16 h = __float2bfloat16(f);  // RNE
  return __builtin_bit_cast(short, h);
}
__device__ __forceinline__ float sigm(float x) { return 1.0f / (1.0f + expf(-x)); }

__device__ __forceinline__ float lif4(float a) {
  float v = 0.0f, acc = 0.0f;
#pragma unroll
  for (int i = 0; i < 4; ++i) {
    v += (a - v) * 0.5f;
    float s = (v >= 1.0f) ? 1.0f : 0.0f;
    acc += s;
    v *= (1.0f - s);
  }
  return acc * 0.25f;
}

__device__ __forceinline__ void gload16(const void* g, void* l) {
  __builtin_amdgcn_global_load_lds(
      (__attribute__((address_space(1))) void*)(g),
      (__attribute__((address_space(3))) void*)(l), 16, 0, 0);
}

template <int N>
__device__ __forceinline__ void waitv() {
  if constexpr (N == 0)  asm volatile("s_waitcnt vmcnt(0)" ::: "memory");
  else if constexpr (N == 2)  asm volatile("s_waitcnt vmcnt(2)" ::: "memory");
  else if constexpr (N == 4)  asm volatile("s_waitcnt vmcnt(4)" ::: "memory");
  else if constexpr (N == 8)  asm volatile("s_waitcnt vmcnt(8)" ::: "memory");
  else static_assert(N == 0, "unsupported vmcnt");
}
__device__ __forceinline__ void barrier_() {
  asm volatile("s_barrier" ::: "memory");
}

// ---------------- elementwise kernels ----------------

// FUSED concat + ln1 + time-mix blends (one 256-thr block per row).
__global__ __launch_bounds__(256) void ln_mix3(
    const float* __restrict__ x, const float* __restrict__ rt,
    const float* __restrict__ tmk, const float* __restrict__ tmv,
    const float* __restrict__ tmr, float* __restrict__ xc,
    short* __restrict__ xk, short* __restrict__ xv, short* __restrict__ xr) {
  __shared__ float red[256];
  int row = blockIdx.x;
  int t = row & 511, b = row >> 9;
  int tid = threadIdx.x;
  const float* src = (t < 256) ? x + (int64_t)(b * 256 + t) * TC_
                               : rt + (int64_t)(t - 256) * TC_;
  float4 v = ((const float4*)src)[tid];
  ((float4*)(xc + (int64_t)row * TC_))[tid] = v;
  red[tid] = v.x + v.y + v.z + v.w;
  __syncthreads();
  for (int off = 128; off > 0; off >>= 1) {
    if (tid < off) red[tid] += red[tid + off];
    __syncthreads();
  }
  float mean = red[0] * (1.0f / 1024.0f);
  __syncthreads();
  float dx = v.x - mean, dy = v.y - mean, dz = v.z - mean, dw = v.w - mean;
  red[tid] = dx * dx + dy * dy + dz * dz + dw * dw;
  __syncthreads();
  for (int off = 128; off > 0; off >>= 1) {
    if (tid < off) red[tid] += red[tid + off];
    __syncthreads();
  }
  float rs = 1.0f / sqrtf(red[0] * (1.0f / 1024.0f) + 1e-6f);
  float c0 = dx * rs, c1 = dy * rs, c2 = dz * rs, c3 = dw * rs;
  float p0 = 0.f, p1 = 0.f, p2 = 0.f, p3 = 0.f;
  if (t > 0) {  // block-uniform
    int tp = t - 1;
    const float* srcp = (tp < 256) ? x + (int64_t)(b * 256 + tp) * TC_
                                   : rt + (int64_t)(tp - 256) * TC_;
    __syncthreads();
    float4 w4 = ((const float4*)srcp)[tid];
    red[tid] = w4.x + w4.y + w4.z + w4.w;
    __syncthreads();
    for (int off = 128; off > 0; off >>= 1) {
      if (tid < off) red[tid] += red[tid + off];
      __syncthreads();
    }
    float meanp = red[0] * (1.0f / 1024.0f);
    __syncthreads();
    float ex = w4.x - meanp, ey = w4.y - meanp, ez = w4.z - meanp,
          ew = w4.w - meanp;
    red[tid] = ex * ex + ey * ey + ez * ez + ew * ew;
    __syncthreads();
    for (int off = 128; off > 0; off >>= 1) {
      if (tid < off) red[tid] += red[tid + off];
      __syncthreads();
    }
    float rsp = 1.0f / sqrtf(red[0] * (1.0f / 1024.0f) + 1e-6f);
    p0 = ex * rsp; p1 = ey * rsp; p2 = ez * rsp; p3 = ew * rsp;
  }
  int c = tid * 4;
  int64_t o = (int64_t)row * TC_ + c;
  float m0, m1, m2, m3;
  s16x4 ov;
  m0 = tmk[c]; m1 = tmk[c + 1]; m2 = tmk[c + 2]; m3 = tmk[c + 3];
  ov.x = f2b(c0 * m0 + p0 * (1.0f - m0));
  ov.y = f2b(c1 * m1 + p1 * (1.0f - m1));
  ov.z = f2b(c2 * m2 + p2 * (1.0f - m2));
  ov.w = f2b(c3 * m3 + p3 * (1.0f - m3));
  *(s16x4*)(xk + o) = ov;
  m0 = tmv[c]; m1 = tmv[c + 1]; m2 = tmv[c + 2]; m3 = tmv[c + 3];
  ov.x = f2b(c0 * m0 + p0 * (1.0f - m0));
  ov.y = f2b(c1 * m1 + p1 * (1.0f - m1));
  ov.z = f2b(c2 * m2 + p2 * (1.0f - m2));
  ov.w = f2b(c3 * m3 + p3 * (1.0f - m3));
  *(s16x4*)(xv + o) = ov;
  m0 = tmr[c]; m1 = tmr[c + 1]; m2 = tmr[c + 2]; m3 = tmr[c + 3];
  ov.x = f2b(c0 * m0 + p0 * (1.0f - m0));
  ov.y = f2b(c1 * m1 + p1 * (1.0f - m1));
  ov.z = f2b(c2 * m2 + p2 * (1.0f - m2));
  ov.w = f2b(c3 * m3 + p3 * (1.0f - m3));
  *(s16x4*)(xr + o) = ov;
}

// fused ln2 + channel-mix blend (same recompute pattern).
__global__ __launch_bounds__(256) void ln_mix2(const float* __restrict__ xc,
                                               const float* __restrict__ cmk,
                                               const float* __restrict__ cmr,
                                               short* __restrict__ xk,
                                               short* __restrict__ xr) {
  __shared__ float red[256];
  int row = blockIdx.x;
  int t = row & 511;
  int tid = threadIdx.x;
  float4 v = ((const float4*)(xc + (int64_t)row * TC_))[tid];
  red[tid] = v.x + v.y + v.z + v.w;
  __syncthreads();
  for (int off = 128; off > 0; off >>= 1) {
    if (tid < off) red[tid] += red[tid + off];
    __syncthreads();
  }
  float mean = red[0] * (1.0f / 1024.0f);
  __syncthreads();
  float dx = v.x - mean, dy = v.y - mean, dz = v.z - mean, dw = v.w - mean;
  red[tid] = dx * dx + dy * dy + dz * dz + dw * dw;
  __syncthreads();
  for (int off = 128; off > 0; off >>= 1) {
    if (tid < off) red[tid] += red[tid + off];
    __syncthreads();
  }
  float rs = 1.0f / sqrtf(red[0] * (1.0f / 1024.0f) + 1e-6f);
  float c0 = dx * rs, c1 = dy * rs, c2 = dz * rs, c3 = dw * rs;
  float p0 = 0.f, p1 = 0.f, p2 = 0.f, p3 = 0.f;
  if (t > 0) {
    __syncthreads();
    float4 w4 = ((const float4*)(xc + (int64_t)(row - 1) * TC_))[tid];
    red[tid] = w4.x + w4.y + w4.z + w4.w;
    __syncthreads();
    for (int off = 128; off > 0; off >>= 1) {
      if (tid < off) red[tid] += red[tid + off];
      __syncthreads();
    }
    float meanp = red[0] * (1.0f / 1024.0f);
    __syncthreads();
    float ex = w4.x - meanp, ey = w4.y - meanp, ez = w4.z - meanp,
          ew = w4.w - meanp;
    red[tid] = ex * ex + ey * ey + ez * ez + ew * ew;
    __syncthreads();
    for (int off = 128; off > 0; off >>= 1) {
      if (tid < off) red[tid] += red[tid + off];
      __syncthreads();
    }
    float rsp = 1.0f / sqrtf(red[0] * (1.0f / 1024.0f) + 1e-6f);
    p0 = ex * rsp; p1 = ey * rsp; p2 = ez * rsp; p3 = ew * rsp;
  }
  int c = tid * 4;
  float k0 = cmk[c], k1 = cmk[c + 1], k2 = cmk[c + 2], k3 = cmk[c + 3];
  float r0 = cmr[c], r1 = cmr[c + 1], r2 = cmr[c + 2], r3 = cmr[c + 3];
  s16x4 ok, orr;
  ok.x = f2b(c0 * k0 + p0 * (1.0f - k0));
  ok.y = f2b(c1 * k1 + p1 * (1.0f - k1));
  ok.z = f2b(c2 * k2 + p2 * (1.0f - k2));
  ok.w = f2b(c3 * k3 + p3 * (1.0f - k3));
  orr.x = f2b(c0 * r0 + p0 * (1.0f - r0));
  orr.y = f2b(c1 * r1 + p1 * (1.0f - r1));
  orr.z = f2b(c2 * r2 + p2 * (1.0f - r2));
  orr.w = f2b(c3 * r3 + p3 * (1.0f - r3));
  *(s16x4*)(xk + (int64_t)row * TC_ + c) = ok;
  *(s16x4*)(xr + (int64_t)row * TC_ + c) = orr;
}

// rtok rows (per b: rows 256..511 of XC) f32 -> bf16 contiguous (B,256,C)
__global__ __launch_bounds__(256) void cvt_rtok(const float* __restrict__ xc,
                                                short* __restrict__ dst) {
  int i = blockIdx.x * 256 + threadIdx.x;  // short8 idx
  int b = i >> 15;
  int rem = i & 32767;
  const float* s = xc + (int64_t)b * 524288 + 262144 + (int64_t)rem * 8;
  float4 a = *(const float4*)s;
  float4 c = *(const float4*)(s + 4);
  bf16x8 o;
  o[0] = f2b(a.x); o[1] = f2b(a.y); o[2] = f2b(a.z); o[3] = f2b(a.w);
  o[4] = f2b(c.x); o[5] = f2b(c.y); o[6] = f2b(c.z); o[7] = f2b(c.w);
  *(bf16x8*)(dst + (int64_t)i * 8) = o;
}

// ONE launch: convert 9 weight arrays f32->bf16 + fused Wam row-sum.
__global__ __launch_bounds__(256) void cvt_all(
    const float* __restrict__ Wk, const float* __restrict__ Wv,
    const float* __restrict__ Wr, const float* __restrict__ Wo,
    const float* __restrict__ Wcr, const float* __restrict__ Wcv,
    const float* __restrict__ Wrm, const float* __restrict__ Wam,
    const float* __restrict__ Wck,
    short* __restrict__ bWk, short* __restrict__ bWv, short* __restrict__ bWr,
    short* __restrict__ bWo, short* __restrict__ bWcr, short* __restrict__ bWcv,
    short* __restrict__ bWrm, short* __restrict__ bWam,
    short* __restrict__ bWck, float* __restrict__ S) {
  int bid = blockIdx.x;
  if (bid >= 4864 && bid < 5120) {  // Wam row-sums
    int row = (bid - 4864) * 4 + (threadIdx.x >> 6);
    int lane = threadIdx.x & 63;
    float4 v = ((const float4*)(Wam + (int64_t)row * 256))[lane];
    float s = v.x + v.y + v.z + v.w;
    for (int off = 32; off > 0; off >>= 1) s += __shfl_down(s, off);
    if (lane == 0) S[row] = s;
    return;
  }
  const float* src; short* dst; int base;
  if (bid < 512)       { src = Wk;  dst = bWk;  base = bid; }
  else if (bid < 1024) { src = Wv;  dst = bWv;  base = bid - 512; }
  else if (bid < 1536) { src = Wr;  dst = bWr;  base = bid - 1024; }
  else if (bid < 2048) { src = Wo;  dst = bWo;  base = bid - 1536; }
  else if (bid < 2560) { src = Wcr; dst = bWcr; base = bid - 2048; }
  else if (bid < 4608) { src = Wcv; dst = bWcv; base = bid - 2560; }
  else if (bid < 4736) { src = Wrm; dst = bWrm; base = bid - 4608; }
  else if (bid < 4864) { src = Wam; dst = bWam; base = bid - 4736; }
  else                 { src = Wck; dst = bWck; base = bid - 5120; }
  int64_t i = ((int64_t)base * 256 + threadIdx.x) * 8;
  float4 a = *(const float4*)(src + i);
  float4 b = *(const float4*)(src + i + 4);
  bf16x8 o;
  o[0] = f2b(a.x); o[1] = f2b(a.y); o[2] = f2b(a.z); o[3] = f2b(a.w);
  o[4] = f2b(b.x); o[5] = f2b(b.y); o[6] = f2b(b.z); o[7] = f2b(b.w);
  *(bf16x8*)(dst + i) = o;
}

// ---------------- wkv chunked parallel scan ----------------
__global__ __launch_bounds__(256) void wkv_p1(const float* __restrict__ td,
                                              const short* __restrict__ K,
                                              const short* __restrict__ V,
                                              float* __restrict__ Ca,
                                              float* __restrict__ Da,
                                              float* __restrict__ Qa) {
  int bx = blockIdx.x;
  int ch = bx >> 5;
  int b = (bx >> 2) & 7;
  int c = (bx & 3) * 256 + threadIdx.x;
  float w = -expf(td[c]);
  float aa = 0.0f, bb = 0.0f, pp = -1e38f;
  int64_t base = ((int64_t)b * TT_ + ch * WKV_L) * TC_ + c;
#pragma unroll
  for (int t = 0; t < WKV_L; ++t) {
    int64_t o = base + (int64_t)t * TC_;
    float kt = b2f(K[o]), vt = b2f(V[o]);
    float ww2 = pp + w;
    float p2 = fmaxf(ww2, kt);
    float e1 = expf(ww2 - p2);
    float e2 = expf(kt - p2);
    aa = e1 * aa + e2 * vt;
    bb = e1 * bb + e2;
    pp = p2;
  }
  int idx = ch * 8192 + b * 1024 + c;
  Ca[idx] = aa; Da[idx] = bb; Qa[idx] = pp;
}

__global__ __launch_bounds__(256) void wkv_p2(const float* __restrict__ td,
                                              const float* __restrict__ Ca,
                                              const float* __restrict__ Da,
                                              const float* __restrict__ Qa,
                                              float* __restrict__ Aa,
                                              float* __restrict__ Ba,
                                              float* __restrict__ Pa) {
  int i = blockIdx.x * 256 + threadIdx.x;
  int c = i & (TC_ - 1);
  float wL = -expf(td[c]) * (float)WKV_L;
  float aa = 0.0f, bb = 0.0f, pp = -1e38f;
#pragma unroll 4
  for (int ch = 0; ch < WKV_NCH; ++ch) {
    int idx = ch * 8192 + i;
    Aa[idx] = aa; Ba[idx] = bb; Pa[idx] = pp;
    float ppw = pp + wL;
    float q = Qa[idx];
    float p2 = fmaxf(ppw, q);
    float ea = expf(ppw - p2);
    float eb = expf(q - p2);
    aa = aa * ea + Ca[idx] * eb;
    bb = bb * ea + Da[idx] * eb;
    pp = p2;
  }
}

__global__ __launch_bounds__(256) void wkv_p3(const float* __restrict__ td,
                                              const float* __restrict__ tf,
                                              const short* __restrict__ K,
                                              const short* __restrict__ V,
                                              const short* __restrict__ SR,
                                              short* __restrict__ SRY,
                                              const float* __restrict__ Aa,
                                              const float* __restrict__ Ba,
                                              const float* __restrict__ Pa) {
  int bx = blockIdx.x;
  int ch = bx >> 5;
  int b = (bx >> 2) & 7;
  int c = (bx & 3) * 256 + threadIdx.x;
  float w = -expf(td[c]);
  float u = tf[c];
  int idx = ch * 8192 + b * 1024 + c;
  float aa = Aa[idx], bb = Ba[idx], pp = Pa[idx];
  int64_t base = ((int64_t)b * TT_ + ch * WKV_L) * TC_ + c;
#pragma unroll
  for (int t = 0; t < WKV_L; ++t) {
    int64_t o = base + (int64_t)t * TC_;
    float kt = b2f(K[o]), vt = b2f(V[o]);
    float ww = u + kt;
    float p = fmaxf(pp, ww);
    float E1 = expf(pp - p);
    float E2 = expf(ww - p);
    float y = (E1 * aa + E2 * vt) / (E1 * bb + E2);
    SRY[o] = f2b(y * b2f(SR[o]));
    float ww2 = pp + w;
    float p2 = fmaxf(ww2, kt);
    float e1 = expf(ww2 - p2);
    float e2 = expf(kt - p2);
    aa = e1 * aa + e2 * vt;
    bb = e1 * bb + e2;
    pp = p2;
  }
}

// ------- 2-phase, 4-deep-ring MFMA GEMM, 128x128 (N=1024 shapes) --------
// Evolution of R19's gemm2p: compacted LDS (32 KB/tile buffer) -> 4-tile
// ring in 128 KB; prologue stages 3 tiles (12 loads), steady state keeps
// 3 tiles (~2 tile-times ~5600 cyc) in flight to cover L3/HBM latency on
// the staging loads (per-XCD working set 12 MB > 4 MB L2 -> B re-reads
// miss to L3; the old 1-phase lookahead only covered L2). ONE vmcnt(8) +
// ONE barrier per K-tile (P0/P1 read tile t, write tile t+3 -- disjoint;
// cross-tile LDS reuse guarded by the end-of-tile barrier; end-of-tile-t
// wait retires tile t+1's 4 loads, leaving t+2,t+3 = 8 outstanding).
// EPI: 1 sigmoid bf16; 4 XC += lif4(acc); 5 XC += lif4(acc * srr(e3)).
template <int EPI>
__global__ __launch_bounds__(512, 1) void gemm2p(
    const short* __restrict__ A, const short* __restrict__ B,
    void* __restrict__ Cp, int M, int N, int K, int Kst,
    const void* __restrict__ e3) {
  __shared__ short lds[4 * 16384];  // ring of 4: [A_k0 4K][A_k1 4K][B_k0][B_k1]
  const int tid = threadIdx.x;

  const unsigned gx = gridDim.x, gy = gridDim.y;
  const unsigned nwg = gx * gy;
  const unsigned lin = blockIdx.x + gx * blockIdx.y;
  const unsigned cs = nwg >> 3;
  const unsigned nl = (lin & 7) * cs + (lin >> 3);
  const unsigned bxs = nl % gx;
  const unsigned bys = nl / gx;

  const int brow = bys * 128;
  const int bcol = bxs * 128;

  const int srow = ((tid >> 6) << 4) + (tid & 15);
  const int skc = ((tid >> 4) & 3) * 8;
  const short* gA = A + (int64_t)(brow + srow) * Kst + skc;
  const short* gB = B + (int64_t)(bcol + srow) * Kst + skc;

  const int lane = tid & 63, wid = tid >> 6;
  const int wr = wid >> 2, wc = wid & 3;

  f32x4 acc[4][2] = {};

#define RD_A(rb, kh, m) \
  (*(const bf16x8*)(lds + (rb) * 16384 + (kh) * 4096 + (wr * 4 + (m)) * 512 + lane * 8))
#define RD_B(rb, kh, n) \
  (*(const bf16x8*)(lds + (rb) * 16384 + 8192 + (kh) * 4096 + (wc * 2 + (n)) * 512 + lane * 8))
#define ST_A(sb, kh, kt) \
  gload16(gA + (kt) * 64 + (kh) * 32, lds + (sb) * 16384 + (kh) * 4096 + tid * 8)
#define ST_B(sb, kh, kt) \
  gload16(gB + (kt) * 64 + (kh) * 32, lds + (sb) * 16384 + 8192 + (kh) * 4096 + tid * 8)
#define MM(am, bn, i, j) \
  acc[i][j] = __builtin_amdgcn_mfma_f32_16x16x32_bf16(am, bn, acc[i][j], 0, 0, 0)

  const int nt = K / 64;  // >= 16 for all uses
  // prologue: stage tiles 0,1,2 (order per tile: A0,B0,A1,B1)
#pragma unroll
  for (int p = 0; p < 3; ++p) {
    ST_A(p, 0, p); ST_B(p, 0, p); ST_A(p, 1, p); ST_B(p, 1, p);
  }
  waitv<8>();  // tile0's 4 retired; tiles 1,2 (8) in flight
  barrier_();

  for (int t = 0; t < nt - 3; ++t) {
    const int rb = t & 3, sb = (t + 3) & 3, kn = t + 3;
    // P0: k-half 0 (reads tile t, stages tile t+3 h0 -- disjoint buffers)
    {
      bf16x8 a0 = RD_A(rb, 0, 0), a1 = RD_A(rb, 0, 1);
      bf16x8 a2 = RD_A(rb, 0, 2), a3 = RD_A(rb, 0, 3);
      bf16x8 b0 = RD_B(rb, 0, 0), b1 = RD_B(rb, 0, 1);
      ST_A(sb, 0, kn); ST_B(sb, 0, kn);
      MM(a0, b0, 0, 0); MM(a0, b1, 0, 1); MM(a1, b0, 1, 0); MM(a1, b1, 1, 1);
      MM(a2, b0, 2, 0); MM(a2, b1, 2, 1); MM(a3, b0, 3, 0); MM(a3, b1, 3, 1);
    }
    // P1: k-half 1
    {
      bf16x8 a0 = RD_A(rb, 1, 0), a1 = RD_A(rb, 1, 1);
      bf16x8 a2 = RD_A(rb, 1, 2), a3 = RD_A(rb, 1, 3);
      bf16x8 b0 = RD_B(rb, 1, 0), b1 = RD_B(rb, 1, 1);
      ST_A(sb, 1, kn); ST_B(sb, 1, kn);
      MM(a0, b0, 0, 0); MM(a0, b1, 0, 1); MM(a1, b0, 1, 0); MM(a1, b1, 1, 1);
      MM(a2, b0, 2, 0); MM(a2, b1, 2, 1); MM(a3, b0, 3, 0); MM(a3, b1, 3, 1);
    }
    waitv<8>();  // retire tile t+1's 4 loads; t+2,t+3 (8) stay in flight
    barrier_();  // publish + guard LDS reuse of buffer (t+4)&3 == rb
  }
  // epilogue: tiles nt-3, nt-2, nt-1 (resident or draining)
#pragma unroll
  for (int e = 0; e < 3; ++e) {
    const int t = nt - 3 + e, rb = t & 3;
#pragma unroll
    for (int kh = 0; kh < 2; ++kh) {
      bf16x8 a0 = RD_A(rb, kh, 0), a1 = RD_A(rb, kh, 1);
      bf16x8 a2 = RD_A(rb, kh, 2), a3 = RD_A(rb, kh, 3);
      bf16x8 b0 = RD_B(rb, kh, 0), b1 = RD_B(rb, kh, 1);
      MM(a0, b0, 0, 0); MM(a0, b1, 0, 1); MM(a1, b0, 1, 0); MM(a1, b1, 1, 1);
      MM(a2, b0, 2, 0); MM(a2, b1, 2, 1); MM(a3, b0, 3, 0); MM(a3, b1, 3, 1);
    }
    if (e == 0) { waitv<4>(); barrier_(); }
    else if (e == 1) { waitv<0>(); barrier_(); }
  }
#undef RD_A
#undef RD_B
#undef ST_A
#undef ST_B
#undef MM

  const int r0 = brow + wr * 64 + (lane >> 4) * 4;
  const int c0 = bcol + wc * 32 + (lane & 15);
#pragma unroll
  for (int m = 0; m < 4; ++m) {
#pragma unroll
    for (int j = 0; j < 4; ++j) {
      int row = r0 + m * 16 + j;
#pragma unroll
      for (int n = 0; n < 2; ++n) {
        int col = c0 + n * 16;
        float v = acc[m][n][j];
        int64_t idx = (int64_t)row * N + col;
        if (EPI == 1) {
          ((short*)Cp)[idx] = f2b(sigm(v));
        } else if (EPI == 4) {
          float* XC = (float*)Cp;
          XC[idx] = XC[idx] + lif4(v);
        } else if (EPI == 5) {
          float* XC = (float*)Cp;
          float srr = b2f(((const short*)e3)[idx]);
          XC[idx] = XC[idx] + lif4(v * srr);
        }
      }
    }
  }
}

// ---------------- 256x256 4-phase body (shared device function) ---------
// (R17/R18-proven schedule.) epi: 0 plain, 1 sigmoid, 2 relu^2 (bf16 out).
__device__ __forceinline__ void g256_body(
    short* lds, const short* __restrict__ A, const short* __restrict__ B,
    short* __restrict__ Cp, int N, int K, int Kst, int brow, int bcol,
    int epi) {
  const int tid = threadIdx.x;
  const short* gA[2];
  const short* gB[2];
  int loff[2];
#pragma unroll
  for (int c = 0; c < 2; ++c) {
    int p = c * 512 + tid;
    int u = p >> 6, s = p & 63;
    gA[c] = A + (int64_t)(brow + u * 16 + (s & 15)) * Kst + (s >> 4) * 8;
    gB[c] = B + (int64_t)(bcol + u * 16 + (s & 15)) * Kst + (s >> 4) * 8;
    loff[c] = p * 8;
  }

  const int lane = tid & 63, wid = tid >> 6;
  const int wr = wid >> 2, wc = wid & 3;

  f32x4 acc[8][4] = {};

#define RD_A(rb, kh, m) \
  (*(const bf16x8*)(lds + (rb) * 32768 + (kh) * 8192 + (wr * 8 + (m)) * 512 + lane * 8))
#define RD_B(rb, kh, n) \
  (*(const bf16x8*)(lds + (rb) * 32768 + 16384 + (kh) * 8192 + (wc * 4 + (n)) * 512 + lane * 8))
#define ST_A(sb, kh, kt)                                                     \
  {                                                                          \
    gload16(gA[0] + (kt) * 64 + (kh) * 32,                                   \
            lds + (sb) * 32768 + (kh) * 8192 + loff[0]);                     \
    gload16(gA[1] + (kt) * 64 + (kh) * 32,                                   \
            lds + (sb) * 32768 + (kh) * 8192 + loff[1]);                     \
  }
#define ST_B(sb, kh, kt)                                                     \
  {                                                                          \
    gload16(gB[0] + (kt) * 64 + (kh) * 32,                                   \
            lds + (sb) * 32768 + 16384 + (kh) * 8192 + loff[0]);             \
    gload16(gB[1] + (kt) * 64 + (kh) * 32,                                   \
            lds + (sb) * 32768 + 16384 + (kh) * 8192 + loff[1]);             \
  }
#define MM(am, bn, i, j) \
  acc[i][j] = __builtin_amdgcn_mfma_f32_16x16x32_bf16(am, bn, acc[i][j], 0, 0, 0)

  const int nt = K / 64;
  ST_A(0, 0, 0); ST_B(0, 0, 0); ST_A(0, 1, 0); ST_B(0, 1, 0);
  waitv<4>();
  barrier_();

  for (int t = 0; t < nt - 1; ++t) {
    const int rb = t & 1, sb = rb ^ 1, kn = t + 1;
    bf16x8 b0, b1, b2, b3;
    {
      bf16x8 a0 = RD_A(rb, 0, 0), a1 = RD_A(rb, 0, 1);
      bf16x8 a2 = RD_A(rb, 0, 2), a3 = RD_A(rb, 0, 3);
      b0 = RD_B(rb, 0, 0); b1 = RD_B(rb, 0, 1);
      b2 = RD_B(rb, 0, 2); b3 = RD_B(rb, 0, 3);
      ST_A(sb, 0, kn);
      MM(a0, b0, 0, 0); MM(a0, b1, 0, 1); MM(a0, b2, 0, 2); MM(a0, b3, 0, 3);
      MM(a1, b0, 1, 0); MM(a1, b1, 1, 1); MM(a1, b2, 1, 2); MM(a1, b3, 1, 3);
      MM(a2, b0, 2, 0); MM(a2, b1, 2, 1); MM(a2, b2, 2, 2); MM(a2, b3, 2, 3);
      MM(a3, b0, 3, 0); MM(a3, b1, 3, 1); MM(a3, b2, 3, 2); MM(a3, b3, 3, 3);
      barrier_();
    }
    {
      bf16x8 a4 = RD_A(rb, 0, 4), a5 = RD_A(rb, 0, 5);
      bf16x8 a6 = RD_A(rb, 0, 6), a7 = RD_A(rb, 0, 7);
      ST_B(sb, 0, kn);
      MM(a4, b0, 4, 0); MM(a4, b1, 4, 1); MM(a4, b2, 4, 2); MM(a4, b3, 4, 3);
      MM(a5, b0, 5, 0); MM(a5, b1, 5, 1); MM(a5, b2, 5, 2); MM(a5, b3, 5, 3);
      MM(a6, b0, 6, 0); MM(a6, b1, 6, 1); MM(a6, b2, 6, 2); MM(a6, b3, 6, 3);
      MM(a7, b0, 7, 0); MM(a7, b1, 7, 1); MM(a7, b2, 7, 2); MM(a7, b3, 7, 3);
      waitv<4>();
      barrier_();
    }
    {
      bf16x8 a0 = RD_A(rb, 1, 0), a1 = RD_A(rb, 1, 1);
      bf16x8 a2 = RD_A(rb, 1, 2), a3 = RD_A(rb, 1, 3);
      b0 = RD_B(rb, 1, 0); b1 = RD_B(rb, 1, 1);
      b2 = RD_B(rb, 1, 2); b3 = RD_B(rb, 1, 3);
      ST_A(sb, 1, kn);
      MM(a0, b0, 0, 0); MM(a0, b1, 0, 1); MM(a0, b2, 0, 2); MM(a0, b3, 0, 3);
      MM(a1, b0, 1, 0); MM(a1, b1, 1, 1); MM(a1, b2, 1, 2); MM(a1, b3, 1, 3);
      MM(a2, b0, 2, 0); MM(a2, b1, 2, 1); MM(a2, b2, 2, 2); MM(a2, b3, 2, 3);
      MM(a3, b0, 3, 0); MM(a3, b1, 3, 1); MM(a3, b2, 3, 2); MM(a3, b3, 3, 3);
      barrier_();
    }
    {
      bf16x8 a4 = RD_A(rb, 1, 4), a5 = RD_A(rb, 1, 5);
      bf16x8 a6 = RD_A(rb, 1, 6), a7 = RD_A(rb, 1, 7);
      ST_B(sb, 1, kn);
      MM(a4, b0, 4, 0); MM(a4, b1, 4, 1); MM(a4, b2, 4, 2); MM(a4, b3, 4, 3);
      MM(a5, b0, 5, 0); MM(a5, b1, 5, 1); MM(a5, b2, 5, 2); MM(a5, b3, 5, 3);
      MM(a6, b0, 6, 0); MM(a6, b1, 6, 1); MM(a6, b2, 6, 2); MM(a6, b3, 6, 3);
      MM(a7, b0, 7, 0); MM(a7, b1, 7, 1); MM(a7, b2, 7, 2); MM(a7, b3, 7, 3);
      waitv<4>();
      barrier_();
    }
  }
  {
    waitv<0>();
    barrier_();
    const int rb = (nt - 1) & 1;
#pragma unroll
    for (int kh = 0; kh < 2; ++kh) {
      bf16x8 b0 = RD_B(rb, kh, 0), b1 = RD_B(rb, kh, 1);
      bf16x8 b2 = RD_B(rb, kh, 2), b3 = RD_B(rb, kh, 3);
#pragma unroll
      for (int m = 0; m < 8; ++m) {
        bf16x8 am = RD_A(rb, kh, m);
        MM(am, b0, m, 0); MM(am, b1, m, 1);
        MM(am, b2, m, 2); MM(am, b3, m, 3);
      }
    }
  }
#undef RD_A
#undef RD_B
#undef ST_A
#undef ST_B
#undef MM

  const int r0 = brow + wr * 128 + (lane >> 4) * 4;
  const int c0 = bcol + wc * 64 + (lane & 15);
#pragma unroll
  for (int m = 0; m < 8; ++m) {
#pragma unroll
    for (int j = 0; j < 4; ++j) {
      int row = r0 + m * 16 + j;
#pragma unroll
      for (int n = 0; n < 4; ++n) {
        int col = c0 + n * 16;
        float v = acc[m][n][j];
        if (epi == 1) v = sigm(v);
        else if (epi == 2) { v = fmaxf(v, 0.0f); v = v * v; }
        Cp[(int64_t)row * N + col] = f2b(v);
      }
    }
  }
}

// tmix wrapper: z-batched 256^2 (grid 4x16x3), epi = (bz==2 ? sigmoid : 0)
__global__ __launch_bounds__(512, 1) void gemm256_z(
    const short* __restrict__ A, const short* __restrict__ B,
    short* __restrict__ C, int64_t sA, int64_t sB, int64_t sC) {
  __shared__ short lds[2 * 32768];
  const unsigned gx = gridDim.x, gy = gridDim.y;
  const unsigned nwg = gx * gy * gridDim.z;
  const unsigned lin = blockIdx.x + gx * (blockIdx.y + gy * blockIdx.z);
  const unsigned cs = nwg >> 3;
  const unsigned nl = (lin & 7) * cs + (lin >> 3);
  const unsigned bxs = nl % gx;
  const unsigned tmp = nl / gx;
  const unsigned bys = tmp % gy;
  const unsigned bz = tmp / gy;
  g256_body(lds, A + bz * sA, B + bz * sB, C + bz * sC, 1024, 1024, 1024,
            bys * 256, bxs * 256, bz == 2 ? 1 : 0);
}

// H wrapper: 256^2 (grid 16x16), relu^2 epilogue.
__global__ __launch_bounds__(512, 1) void gemm256_h(
    const short* __restrict__ A, const short* __restrict__ B,
    short* __restrict__ C) {
  __shared__ short lds[2 * 32768];
  const unsigned gx = gridDim.x, gy = gridDim.y;
  const unsigned nwg = gx * gy;
  const unsigned lin = blockIdx.x + gx * blockIdx.y;
  const unsigned cs = nwg >> 3;
  const unsigned nl = (lin & 7) * cs + (lin >> 3);
  const unsigned bxs = nl % gx;
  const unsigned bys = nl / gx;
  g256_body(lds, A, B, C, 4096, 1024, 1024, bys * 256, bxs * 256, 2);
}

// ---------------- LDS MFMA GEMM (2-barrier path: tails) -----------------
template <int BM, int BN, int EPI, int D, int MINW>
__global__ __launch_bounds__(256, MINW) void gemm_bf16(
    const short* __restrict__ A, const short* __restrict__ B,
    void* __restrict__ Cp, int M, int N, int K, int Kst,
    int64_t sA, int64_t sB, int64_t sC,
    const float* __restrict__ e0, const float* __restrict__ e1,
    const float* __restrict__ e2, const void* __restrict__ e3, int64_t sE) {
  constexpr int MF = BM / 32;
  constexpr int NF = BN / 32;
  constexpr int ASLOT = BM / 64;
  constexpr int BSLOT = BN / 64;
  constexpr int NL = ASLOT + BSLOT;
  constexpr int SBUF = (BM + BN) * 32;
  __shared__ short lds[D * SBUF];
  const int tid = threadIdx.x;

  const unsigned gx = gridDim.x, gy = gridDim.y;
  const unsigned nwg = gx * gy * gridDim.z;
  const unsigned lin = blockIdx.x + gx * (blockIdx.y + gy * blockIdx.z);
  const unsigned cs = nwg >> 3;
  const unsigned nl = (lin & 7) * cs + (lin >> 3);
  const unsigned bxs = nl % gx;
  const unsigned tmp = nl / gx;
  const unsigned bys = tmp % gy;
  const unsigned bz = tmp / gy;

  const int brow = bys * BM;
  const int bcol = bxs * BN;
  const short* Ab = A + bz * sA;
  const short* Bb = B + bz * sB;

  const int srow = ((tid >> 6) << 4) + (tid & 15);
  const int skc = ((tid >> 4) & 3) * 8;
  const short* gA[ASLOT];
  const short* gB[BSLOT];
#pragma unroll
  for (int s = 0; s < ASLOT; ++s)
    gA[s] = Ab + (int64_t)(brow + s * 64 + srow) * Kst + skc;
#pragma unroll
  for (int s = 0; s < BSLOT; ++s)
    gB[s] = Bb + (int64_t)(bcol + s * 64 + srow) * Kst + skc;

  const int lane = tid & 63, wid = tid >> 6;
  const int wr = wid >> 1, wc = wid & 1;

  f32x4 acc[MF][NF] = {};

  auto stage = [&](int buf, int k0) {
    short* d = lds + buf * SBUF;
#pragma unroll
    for (int s = 0; s < ASLOT; ++s)
      gload16(gA[s] + k0, d + s * 2048 + tid * 8);
#pragma unroll
    for (int s = 0; s < BSLOT; ++s)
      gload16(gB[s] + k0, d + BM * 32 + s * 2048 + tid * 8);
  };
  auto compute = [&](int buf) {
    const short* base = lds + buf * SBUF;
    bf16x8 af[MF], bfv[NF];
#pragma unroll
    for (int m = 0; m < MF; ++m)
      af[m] = *(const bf16x8*)(base + (wr * MF + m) * 512 + lane * 8);
#pragma unroll
    for (int n = 0; n < NF; ++n)
      bfv[n] = *(const bf16x8*)(base + BM * 32 + (wc * NF + n) * 512 + lane * 8);
#pragma unroll
    for (int m = 0; m < MF; ++m)
#pragma unroll
      for (int n = 0; n < NF; ++n)
        acc[m][n] = __builtin_amdgcn_mfma_f32_16x16x32_bf16(af[m], bfv[n],
                                                            acc[m][n], 0, 0, 0);
  };

  const int nst = K / 32;
#pragma unroll
  for (int d = 0; d < D - 1; ++d) stage(d, d * 32);
  for (int t = 0; t <= nst - D; ++t) {
    stage((t + D - 1) & (D - 1), (t + D - 1) * 32);
    waitv<(D - 1) * NL>();
    barrier_();
    compute(t & (D - 1));
    barrier_();
  }
  {
    int t = nst - D + 1;
    waitv<0>(); barrier_(); compute(t & (D - 1));
  }

  const int r0 = brow + wr * (BM / 2) + (lane >> 4) * 4;
  const int c0 = bcol + wc * (BN / 2) + (lane & 15);
#pragma unroll
  for (int m = 0; m < MF; ++m) {
#pragma unroll
    for (int j = 0; j < 4; ++j) {
      int row = r0 + m * 16 + j;
#pragma unroll
      for (int n = 0; n < NF; ++n) {
        int col = c0 + n * 16;
        float v = acc[m][n][j];
        int64_t idx = (int64_t)row * N + col;
        if (EPI == 0) {
          ((short*)Cp)[bz * sC + idx] = f2b(v);
        } else if (EPI == 3) {
          float r2 = v + e0[row] * e1[col] + e2[col];
          float xo = ((const float*)e3)[bz * sE + idx];
          ((float*)Cp)[bz * sC + idx] = xo * (1.0f + r2);
        }
      }
    }
  }
}

// ---------------- launch ----------------
extern "C" void kernel_launch(void* const* d_in, const int* in_sizes, int n_in,
                              void* d_out, int out_size, void* d_ws,
                              size_t ws_size, hipStream_t stream) {
  const float* x   = (const float*)d_in[0];
  const float* rt  = (const float*)d_in[1];
  const float* td  = (const float*)d_in[2];
  const float* tf  = (const float*)d_in[3];
  const float* tmk = (const float*)d_in[4];
  const float* tmv = (const float*)d_in[5];
  const float* tmr = (const float*)d_in[6];
  const float* Wk  = (const float*)d_in[7];
  const float* Wv  = (const float*)d_in[8];
  const float* Wr  = (const float*)d_in[9];
  const float* Wo  = (const float*)d_in[10];
  const float* cmk = (const float*)d_in[11];
  const float* cmr = (const float*)d_in[12];
  const float* Wck = (const float*)d_in[13];
  const float* Wcv = (const float*)d_in[14];
  const float* Wcr = (const float*)d_in[15];
  const float* Wrm = (const float*)d_in[16];
  const float* brm = (const float*)d_in[17];
  const float* Wam = (const float*)d_in[18];
  const float* bam = (const float*)d_in[19];
  float* out = (float*)d_out;

  const size_t MB = 1ull << 20;
  uint8_t* W8 = (uint8_t*)d_ws;
  float* XC     = (float*)(W8);                        // 0-16 residual f32
  short* bWck16 = (short*)(W8 + 16 * MB);              // 16-24
  short* S1     = (short*)(W8 + 24 * MB);              // 24-32 xk / SRY / SRR
  short* S2     = (short*)(W8 + 32 * MB);              // 32-40 xv/xk2/rtok,Mt
  short* S3     = (short*)(W8 + 40 * MB);              // 40-48 xr / xr2
  short* bWcv   = (short*)(W8 + 48 * MB);              // 48-56
  short* bWk    = (short*)(W8 + 56 * MB);              // 56-62
  short* bWo    = (short*)(W8 + 62 * MB);
  short* bWcr   = (short*)(W8 + 64 * MB);
  short* bWrm   = (short*)(W8 + 66 * MB);              // 0.5 MB
  short* bWam   = (short*)(W8 + 66 * MB + 512 * 1024); // 0.5 MB
  short* KK     = (short*)(W8 + 67 * MB);              // 67-75
  short* VV     = (short*)(W8 + 75 * MB);              // 75-83
  short* RR     = (short*)(W8 + 83 * MB);              // 83-91
  float* Ca     = (float*)(W8 + 91 * MB);              // wkv temps 91-97
  float* Da     = (float*)(W8 + 92 * MB);
  float* Qa     = (float*)(W8 + 93 * MB);
  float* Aa     = (float*)(W8 + 94 * MB);
  float* Ba     = (float*)(W8 + 95 * MB);
  float* Pa     = (float*)(W8 + 96 * MB);
  short* SRY    = S1;
  short* xk2    = S2;
  short* xr2    = S3;
  short* SRR    = S1;
  short* H16    = KK;                                  // 67-99 (32 MB)
  short* rtok   = S2;                                  // 32-36 (tail)
  short* Mt     = (short*)(W8 + 36 * MB);              // 36-37 (tail)
  float* Sb     = (float*)(W8 + 99 * MB);              // 4 KB

  dim3 blk(256);
  dim3 blk512(512);

  // 0) ALL weight conversions (incl. Wck) + Wam row-sum in one launch
  cvt_all<<<7168, blk, 0, stream>>>(Wk, Wv, Wr, Wo, Wcr, Wcv, Wrm, Wam, Wck,
                                    bWk, bWk + 1048576, bWk + 2097152, bWo,
                                    bWcr, bWcv, bWrm, bWam, bWck16, Sb);

  // 1) FUSED concat + ln1 + time-mix blends -> XC, S1, S2, S3
  ln_mix3<<<TB_ * TT_, blk, 0, stream>>>(x, rt, tmk, tmv, tmr, XC, S1, S2, S3);

  // 2) fused z=3 time-mix: KK/VV/RR   (256^2 4-phase, grid 192, z-batched)
  gemm256_z<<<dim3(4, 16, 3), blk512, 0, stream>>>(
      S1, bWk, KK, 4194304, 1048576, 4194304);
  // 3) wkv chunked scan -> SRY (=S1)
  wkv_p1<<<WKV_NCH * TB_ * 4, blk, 0, stream>>>(td, KK, VV, Ca, Da, Qa);
  wkv_p2<<<32, blk, 0, stream>>>(td, Ca, Da, Qa, Aa, Ba, Pa);
  wkv_p3<<<WKV_NCH * TB_ * 4, blk, 0, stream>>>(td, tf, KK, VV, RR, SRY,
                                                Aa, Ba, Pa);
  // 4) att: XC += lif(SRY*Wo^T)   (2-phase 4-deep ring, 8 waves)
  gemm2p<4><<<dim3(8, 32), blk512, 0, stream>>>(
      SRY, bWo, XC, 4096, 1024, 1024, 1024, nullptr);
  // 5) fused ln2+mix2 -> xk2(S2), xr2(S3)
  ln_mix2<<<TB_ * TT_, blk, 0, stream>>>(XC, cmk, cmr, xk2, xr2);
  // 6) SRR = sigm(xr2*Wcr^T) -> S1   (2-phase 4-deep)
  gemm2p<1><<<dim3(8, 32), blk512, 0, stream>>>(
      xr2, bWcr, SRR, 4096, 1024, 1024, 1024, nullptr);
  // 7) H = relu^2(xk2*Wck^T) -> H16   (256^2 4-phase, grid 256 = 1 blk/CU)
  gemm256_h<<<dim3(16, 16), blk512, 0, stream>>>(xk2, bWck16, H16);
  // 8) XC += lif(SRR*(H*Wcv^T))   (2-phase 4-deep, K=4096)
  gemm2p<5><<<dim3(8, 32), blk512, 0, stream>>>(
      H16, bWcv, XC, 4096, 1024, 4096, 4096, SRR);
  // 9) tail
  cvt_rtok<<<1024, blk, 0, stream>>>(XC, rtok);
  gemm_bf16<64, 64, 0, 2, 2><<<dim3(4, 4, 8), blk, 0, stream>>>(
      bWrm, rtok, Mt, 256, 256, 1024, 1024, 0, (int64_t)256 * 1024,
      (int64_t)256 * 256, nullptr, nullptr, nullptr, nullptr, 0);
  gemm_bf16<64, 64, 3, 2, 2><<<dim3(16, 4, 8), blk, 0, stream>>>(
      Mt, bWam, out, 256, 1024, 256, 256, (int64_t)256 * 256, 0,
      (int64_t)256 * 1024, brm, Sb, bam, XC, (int64_t)512 * 1024);
}

// Round 27
// 293.633 us; speedup vs baseline: 1.0017x; 1.0017x over previous
//
#include <hip/hip_runtime.h>
#include <hip/hip_bf16.h>
#include <math.h>
#include <stdint.h>

// B=8, P1=256 -> T=512 concat rows, C=1024, H=4096
#define TB_ 8
#define TT_ 512
#define TC_ 1024
#define WKV_NCH 32
#define WKV_L 16

typedef __attribute__((ext_vector_type(8))) short bf16x8;
typedef __attribute__((ext_vector_type(4))) short s16x4;
typedef __attribute__((ext_vector_type(4))) float f32x4;

__device__ __forceinline__ float b2f(short u) {
  union { unsigned int i; float f; } x;
  x.i = ((unsigned int)(unsigned short)u) << 16;
  return x.f;
}
__device__ __forceinline__ short f2b(float f) {
  __hip_bfloat16 h = __float2bfloat16(f);  // RNE
  return __builtin_bit_cast(short, h);
}
__device__ __forceinline__ float sigm(float x) { return 1.0f / (1.0f + expf(-x)); }

__device__ __forceinline__ float lif4(float a) {
  float v = 0.0f, acc = 0.0f;
#pragma unroll
  for (int i = 0; i < 4; ++i) {
    v += (a - v) * 0.5f;
    float s = (v >= 1.0f) ? 1.0f : 0.0f;
    acc += s;
    v *= (1.0f - s);
  }
  return acc * 0.25f;
}

__device__ __forceinline__ void gload16(const void* g, void* l) {
  __builtin_amdgcn_global_load_lds(
      (__attribute__((address_space(1))) void*)(g),
      (__attribute__((address_space(3))) void*)(l), 16, 0, 0);
}

template <int N>
__device__ __forceinline__ void waitv() {
  if constexpr (N == 0)  asm volatile("s_waitcnt vmcnt(0)" ::: "memory");
  else if constexpr (N == 2)  asm volatile("s_waitcnt vmcnt(2)" ::: "memory");
  else if constexpr (N == 4)  asm volatile("s_waitcnt vmcnt(4)" ::: "memory");
  else if constexpr (N == 8)  asm volatile("s_waitcnt vmcnt(8)" ::: "memory");
  else static_assert(N == 0, "unsupported vmcnt");
}
__device__ __forceinline__ void barrier_() {
  asm volatile("s_barrier" ::: "memory");
}

// ---------------- elementwise kernels ----------------

// FUSED concat + ln1 + time-mix blends (one 256-thr block per row).
__global__ __launch_bounds__(256) void ln_mix3(
    const float* __restrict__ x, const float* __restrict__ rt,
    const float* __restrict__ tmk, const float* __restrict__ tmv,
    const float* __restrict__ tmr, float* __restrict__ xc,
    short* __restrict__ xk, short* __restrict__ xv, short* __restrict__ xr) {
  __shared__ float red[256];
  int row = blockIdx.x;
  int t = row & 511, b = row >> 9;
  int tid = threadIdx.x;
  const float* src = (t < 256) ? x + (int64_t)(b * 256 + t) * TC_
                               : rt + (int64_t)(t - 256) * TC_;
  float4 v = ((const float4*)src)[tid];
  ((float4*)(xc + (int64_t)row * TC_))[tid] = v;
  red[tid] = v.x + v.y + v.z + v.w;
  __syncthreads();
  for (int off = 128; off > 0; off >>= 1) {
    if (tid < off) red[tid] += red[tid + off];
    __syncthreads();
  }
  float mean = red[0] * (1.0f / 1024.0f);
  __syncthreads();
  float dx = v.x - mean, dy = v.y - mean, dz = v.z - mean, dw = v.w - mean;
  red[tid] = dx * dx + dy * dy + dz * dz + dw * dw;
  __syncthreads();
  for (int off = 128; off > 0; off >>= 1) {
    if (tid < off) red[tid] += red[tid + off];
    __syncthreads();
  }
  float rs = 1.0f / sqrtf(red[0] * (1.0f / 1024.0f) + 1e-6f);
  float c0 = dx * rs, c1 = dy * rs, c2 = dz * rs, c3 = dw * rs;
  float p0 = 0.f, p1 = 0.f, p2 = 0.f, p3 = 0.f;
  if (t > 0) {  // block-uniform
    int tp = t - 1;
    const float* srcp = (tp < 256) ? x + (int64_t)(b * 256 + tp) * TC_
                                   : rt + (int64_t)(tp - 256) * TC_;
    __syncthreads();
    float4 w4 = ((const float4*)srcp)[tid];
    red[tid] = w4.x + w4.y + w4.z + w4.w;
    __syncthreads();
    for (int off = 128; off > 0; off >>= 1) {
      if (tid < off) red[tid] += red[tid + off];
      __syncthreads();
    }
    float meanp = red[0] * (1.0f / 1024.0f);
    __syncthreads();
    float ex = w4.x - meanp, ey = w4.y - meanp, ez = w4.z - meanp,
          ew = w4.w - meanp;
    red[tid] = ex * ex + ey * ey + ez * ez + ew * ew;
    __syncthreads();
    for (int off = 128; off > 0; off >>= 1) {
      if (tid < off) red[tid] += red[tid + off];
      __syncthreads();
    }
    float rsp = 1.0f / sqrtf(red[0] * (1.0f / 1024.0f) + 1e-6f);
    p0 = ex * rsp; p1 = ey * rsp; p2 = ez * rsp; p3 = ew * rsp;
  }
  int c = tid * 4;
  int64_t o = (int64_t)row * TC_ + c;
  float m0, m1, m2, m3;
  s16x4 ov;
  m0 = tmk[c]; m1 = tmk[c + 1]; m2 = tmk[c + 2]; m3 = tmk[c + 3];
  ov.x = f2b(c0 * m0 + p0 * (1.0f - m0));
  ov.y = f2b(c1 * m1 + p1 * (1.0f - m1));
  ov.z = f2b(c2 * m2 + p2 * (1.0f - m2));
  ov.w = f2b(c3 * m3 + p3 * (1.0f - m3));
  *(s16x4*)(xk + o) = ov;
  m0 = tmv[c]; m1 = tmv[c + 1]; m2 = tmv[c + 2]; m3 = tmv[c + 3];
  ov.x = f2b(c0 * m0 + p0 * (1.0f - m0));
  ov.y = f2b(c1 * m1 + p1 * (1.0f - m1));
  ov.z = f2b(c2 * m2 + p2 * (1.0f - m2));
  ov.w = f2b(c3 * m3 + p3 * (1.0f - m3));
  *(s16x4*)(xv + o) = ov;
  m0 = tmr[c]; m1 = tmr[c + 1]; m2 = tmr[c + 2]; m3 = tmr[c + 3];
  ov.x = f2b(c0 * m0 + p0 * (1.0f - m0));
  ov.y = f2b(c1 * m1 + p1 * (1.0f - m1));
  ov.z = f2b(c2 * m2 + p2 * (1.0f - m2));
  ov.w = f2b(c3 * m3 + p3 * (1.0f - m3));
  *(s16x4*)(xr + o) = ov;
}

// fused ln2 + channel-mix blend (same recompute pattern).
__global__ __launch_bounds__(256) void ln_mix2(const float* __restrict__ xc,
                                               const float* __restrict__ cmk,
                                               const float* __restrict__ cmr,
                                               short* __restrict__ xk,
                                               short* __restrict__ xr) {
  __shared__ float red[256];
  int row = blockIdx.x;
  int t = row & 511;
  int tid = threadIdx.x;
  float4 v = ((const float4*)(xc + (int64_t)row * TC_))[tid];
  red[tid] = v.x + v.y + v.z + v.w;
  __syncthreads();
  for (int off = 128; off > 0; off >>= 1) {
    if (tid < off) red[tid] += red[tid + off];
    __syncthreads();
  }
  float mean = red[0] * (1.0f / 1024.0f);
  __syncthreads();
  float dx = v.x - mean, dy = v.y - mean, dz = v.z - mean, dw = v.w - mean;
  red[tid] = dx * dx + dy * dy + dz * dz + dw * dw;
  __syncthreads();
  for (int off = 128; off > 0; off >>= 1) {
    if (tid < off) red[tid] += red[tid + off];
    __syncthreads();
  }
  float rs = 1.0f / sqrtf(red[0] * (1.0f / 1024.0f) + 1e-6f);
  float c0 = dx * rs, c1 = dy * rs, c2 = dz * rs, c3 = dw * rs;
  float p0 = 0.f, p1 = 0.f, p2 = 0.f, p3 = 0.f;
  if (t > 0) {
    __syncthreads();
    float4 w4 = ((const float4*)(xc + (int64_t)(row - 1) * TC_))[tid];
    red[tid] = w4.x + w4.y + w4.z + w4.w;
    __syncthreads();
    for (int off = 128; off > 0; off >>= 1) {
      if (tid < off) red[tid] += red[tid + off];
      __syncthreads();
    }
    float meanp = red[0] * (1.0f / 1024.0f);
    __syncthreads();
    float ex = w4.x - meanp, ey = w4.y - meanp, ez = w4.z - meanp,
          ew = w4.w - meanp;
    red[tid] = ex * ex + ey * ey + ez * ez + ew * ew;
    __syncthreads();
    for (int off = 128; off > 0; off >>= 1) {
      if (tid < off) red[tid] += red[tid + off];
      __syncthreads();
    }
    float rsp = 1.0f / sqrtf(red[0] * (1.0f / 1024.0f) + 1e-6f);
    p0 = ex * rsp; p1 = ey * rsp; p2 = ez * rsp; p3 = ew * rsp;
  }
  int c = tid * 4;
  float k0 = cmk[c], k1 = cmk[c + 1], k2 = cmk[c + 2], k3 = cmk[c + 3];
  float r0 = cmr[c], r1 = cmr[c + 1], r2 = cmr[c + 2], r3 = cmr[c + 3];
  s16x4 ok, orr;
  ok.x = f2b(c0 * k0 + p0 * (1.0f - k0));
  ok.y = f2b(c1 * k1 + p1 * (1.0f - k1));
  ok.z = f2b(c2 * k2 + p2 * (1.0f - k2));
  ok.w = f2b(c3 * k3 + p3 * (1.0f - k3));
  orr.x = f2b(c0 * r0 + p0 * (1.0f - r0));
  orr.y = f2b(c1 * r1 + p1 * (1.0f - r1));
  orr.z = f2b(c2 * r2 + p2 * (1.0f - r2));
  orr.w = f2b(c3 * r3 + p3 * (1.0f - r3));
  *(s16x4*)(xk + (int64_t)row * TC_ + c) = ok;
  *(s16x4*)(xr + (int64_t)row * TC_ + c) = orr;
}

// rtok rows (per b: rows 256..511 of XC) f32 -> bf16 contiguous (B,256,C)
__global__ __launch_bounds__(256) void cvt_rtok(const float* __restrict__ xc,
                                                short* __restrict__ dst) {
  int i = blockIdx.x * 256 + threadIdx.x;  // short8 idx
  int b = i >> 15;
  int rem = i & 32767;
  const float* s = xc + (int64_t)b * 524288 + 262144 + (int64_t)rem * 8;
  float4 a = *(const float4*)s;
  float4 c = *(const float4*)(s + 4);
  bf16x8 o;
  o[0] = f2b(a.x); o[1] = f2b(a.y); o[2] = f2b(a.z); o[3] = f2b(a.w);
  o[4] = f2b(c.x); o[5] = f2b(c.y); o[6] = f2b(c.z); o[7] = f2b(c.w);
  *(bf16x8*)(dst + (int64_t)i * 8) = o;
}

// ONE launch: convert 9 weight arrays f32->bf16 + fused Wam row-sum.
__global__ __launch_bounds__(256) void cvt_all(
    const float* __restrict__ Wk, const float* __restrict__ Wv,
    const float* __restrict__ Wr, const float* __restrict__ Wo,
    const float* __restrict__ Wcr, const float* __restrict__ Wcv,
    const float* __restrict__ Wrm, const float* __restrict__ Wam,
    const float* __restrict__ Wck,
    short* __restrict__ bWk, short* __restrict__ bWv, short* __restrict__ bWr,
    short* __restrict__ bWo, short* __restrict__ bWcr, short* __restrict__ bWcv,
    short* __restrict__ bWrm, short* __restrict__ bWam,
    short* __restrict__ bWck, float* __restrict__ S) {
  int bid = blockIdx.x;
  if (bid >= 4864 && bid < 5120) {  // Wam row-sums
    int row = (bid - 4864) * 4 + (threadIdx.x >> 6);
    int lane = threadIdx.x & 63;
    float4 v = ((const float4*)(Wam + (int64_t)row * 256))[lane];
    float s = v.x + v.y + v.z + v.w;
    for (int off = 32; off > 0; off >>= 1) s += __shfl_down(s, off);
    if (lane == 0) S[row] = s;
    return;
  }
  const float* src; short* dst; int base;
  if (bid < 512)       { src = Wk;  dst = bWk;  base = bid; }
  else if (bid < 1024) { src = Wv;  dst = bWv;  base = bid - 512; }
  else if (bid < 1536) { src = Wr;  dst = bWr;  base = bid - 1024; }
  else if (bid < 2048) { src = Wo;  dst = bWo;  base = bid - 1536; }
  else if (bid < 2560) { src = Wcr; dst = bWcr; base = bid - 2048; }
  else if (bid < 4608) { src = Wcv; dst = bWcv; base = bid - 2560; }
  else if (bid < 4736) { src = Wrm; dst = bWrm; base = bid - 4608; }
  else if (bid < 4864) { src = Wam; dst = bWam; base = bid - 4736; }
  else                 { src = Wck; dst = bWck; base = bid - 5120; }
  int64_t i = ((int64_t)base * 256 + threadIdx.x) * 8;
  float4 a = *(const float4*)(src + i);
  float4 b = *(const float4*)(src + i + 4);
  bf16x8 o;
  o[0] = f2b(a.x); o[1] = f2b(a.y); o[2] = f2b(a.z); o[3] = f2b(a.w);
  o[4] = f2b(b.x); o[5] = f2b(b.y); o[6] = f2b(b.z); o[7] = f2b(b.w);
  *(bf16x8*)(dst + i) = o;
}

// ---------------- wkv chunked parallel scan ----------------
__global__ __launch_bounds__(256) void wkv_p1(const float* __restrict__ td,
                                              const short* __restrict__ K,
                                              const short* __restrict__ V,
                                              float* __restrict__ Ca,
                                              float* __restrict__ Da,
                                              float* __restrict__ Qa) {
  int bx = blockIdx.x;
  int ch = bx >> 5;
  int b = (bx >> 2) & 7;
  int c = (bx & 3) * 256 + threadIdx.x;
  float w = -expf(td[c]);
  float aa = 0.0f, bb = 0.0f, pp = -1e38f;
  int64_t base = ((int64_t)b * TT_ + ch * WKV_L) * TC_ + c;
#pragma unroll
  for (int t = 0; t < WKV_L; ++t) {
    int64_t o = base + (int64_t)t * TC_;
    float kt = b2f(K[o]), vt = b2f(V[o]);
    float ww2 = pp + w;
    float p2 = fmaxf(ww2, kt);
    float e1 = expf(ww2 - p2);
    float e2 = expf(kt - p2);
    aa = e1 * aa + e2 * vt;
    bb = e1 * bb + e2;
    pp = p2;
  }
  int idx = ch * 8192 + b * 1024 + c;
  Ca[idx] = aa; Da[idx] = bb; Qa[idx] = pp;
}

__global__ __launch_bounds__(256) void wkv_p2(const float* __restrict__ td,
                                              const float* __restrict__ Ca,
                                              const float* __restrict__ Da,
                                              const float* __restrict__ Qa,
                                              float* __restrict__ Aa,
                                              float* __restrict__ Ba,
                                              float* __restrict__ Pa) {
  int i = blockIdx.x * 256 + threadIdx.x;
  int c = i & (TC_ - 1);
  float wL = -expf(td[c]) * (float)WKV_L;
  float aa = 0.0f, bb = 0.0f, pp = -1e38f;
#pragma unroll 4
  for (int ch = 0; ch < WKV_NCH; ++ch) {
    int idx = ch * 8192 + i;
    Aa[idx] = aa; Ba[idx] = bb; Pa[idx] = pp;
    float ppw = pp + wL;
    float q = Qa[idx];
    float p2 = fmaxf(ppw, q);
    float ea = expf(ppw - p2);
    float eb = expf(q - p2);
    aa = aa * ea + Ca[idx] * eb;
    bb = bb * ea + Da[idx] * eb;
    pp = p2;
  }
}

__global__ __launch_bounds__(256) void wkv_p3(const float* __restrict__ td,
                                              const float* __restrict__ tf,
                                              const short* __restrict__ K,
                                              const short* __restrict__ V,
                                              const short* __restrict__ SR,
                                              short* __restrict__ SRY,
                                              const float* __restrict__ Aa,
                                              const float* __restrict__ Ba,
                                              const float* __restrict__ Pa) {
  int bx = blockIdx.x;
  int ch = bx >> 5;
  int b = (bx >> 2) & 7;
  int c = (bx & 3) * 256 + threadIdx.x;
  float w = -expf(td[c]);
  float u = tf[c];
  int idx = ch * 8192 + b * 1024 + c;
  float aa = Aa[idx], bb = Ba[idx], pp = Pa[idx];
  int64_t base = ((int64_t)b * TT_ + ch * WKV_L) * TC_ + c;
#pragma unroll
  for (int t = 0; t < WKV_L; ++t) {
    int64_t o = base + (int64_t)t * TC_;
    float kt = b2f(K[o]), vt = b2f(V[o]);
    float ww = u + kt;
    float p = fmaxf(pp, ww);
    float E1 = expf(pp - p);
    float E2 = expf(ww - p);
    float y = (E1 * aa + E2 * vt) / (E1 * bb + E2);
    SRY[o] = f2b(y * b2f(SR[o]));
    float ww2 = pp + w;
    float p2 = fmaxf(ww2, kt);
    float e1 = expf(ww2 - p2);
    float e2 = expf(kt - p2);
    aa = e1 * aa + e2 * vt;
    bb = e1 * bb + e2;
    pp = p2;
  }
}

// ------- 2-phase, 4-deep-ring MFMA GEMM, 128x128 (N=1024 shapes) --------
// (R26 structure.) + T5: s_setprio(1) around each MFMA cluster -- with 2
// waves/SIMD at different phases, the scheduler favors the MFMA-entering
// wave over the load-issuing wave (catalog: +21-39% on phase-interleaved
// 8-wave schedules, null on lockstep -- this is the qualifying structure).
// EPI: 1 sigmoid bf16; 4 XC += lif4(acc); 5 XC += lif4(acc * srr(e3)).
template <int EPI>
__global__ __launch_bounds__(512, 1) void gemm2p(
    const short* __restrict__ A, const short* __restrict__ B,
    void* __restrict__ Cp, int M, int N, int K, int Kst,
    const void* __restrict__ e3) {
  __shared__ short lds[4 * 16384];  // ring of 4: [A_k0 4K][A_k1 4K][B_k0][B_k1]
  const int tid = threadIdx.x;

  const unsigned gx = gridDim.x, gy = gridDim.y;
  const unsigned nwg = gx * gy;
  const unsigned lin = blockIdx.x + gx * blockIdx.y;
  const unsigned cs = nwg >> 3;
  const unsigned nl = (lin & 7) * cs + (lin >> 3);
  const unsigned bxs = nl % gx;
  const unsigned bys = nl / gx;

  const int brow = bys * 128;
  const int bcol = bxs * 128;

  const int srow = ((tid >> 6) << 4) + (tid & 15);
  const int skc = ((tid >> 4) & 3) * 8;
  const short* gA = A + (int64_t)(brow + srow) * Kst + skc;
  const short* gB = B + (int64_t)(bcol + srow) * Kst + skc;

  const int lane = tid & 63, wid = tid >> 6;
  const int wr = wid >> 2, wc = wid & 3;

  f32x4 acc[4][2] = {};

#define RD_A(rb, kh, m) \
  (*(const bf16x8*)(lds + (rb) * 16384 + (kh) * 4096 + (wr * 4 + (m)) * 512 + lane * 8))
#define RD_B(rb, kh, n) \
  (*(const bf16x8*)(lds + (rb) * 16384 + 8192 + (kh) * 4096 + (wc * 2 + (n)) * 512 + lane * 8))
#define ST_A(sb, kh, kt) \
  gload16(gA + (kt) * 64 + (kh) * 32, lds + (sb) * 16384 + (kh) * 4096 + tid * 8)
#define ST_B(sb, kh, kt) \
  gload16(gB + (kt) * 64 + (kh) * 32, lds + (sb) * 16384 + 8192 + (kh) * 4096 + tid * 8)
#define MM(am, bn, i, j) \
  acc[i][j] = __builtin_amdgcn_mfma_f32_16x16x32_bf16(am, bn, acc[i][j], 0, 0, 0)

  const int nt = K / 64;  // >= 16 for all uses
  // prologue: stage tiles 0,1,2 (order per tile: A0,B0,A1,B1)
#pragma unroll
  for (int p = 0; p < 3; ++p) {
    ST_A(p, 0, p); ST_B(p, 0, p); ST_A(p, 1, p); ST_B(p, 1, p);
  }
  waitv<8>();  // tile0's 4 retired; tiles 1,2 (8) in flight
  barrier_();

  for (int t = 0; t < nt - 3; ++t) {
    const int rb = t & 3, sb = (t + 3) & 3, kn = t + 3;
    // P0: k-half 0 (reads tile t, stages tile t+3 h0 -- disjoint buffers)
    {
      bf16x8 a0 = RD_A(rb, 0, 0), a1 = RD_A(rb, 0, 1);
      bf16x8 a2 = RD_A(rb, 0, 2), a3 = RD_A(rb, 0, 3);
      bf16x8 b0 = RD_B(rb, 0, 0), b1 = RD_B(rb, 0, 1);
      ST_A(sb, 0, kn); ST_B(sb, 0, kn);
      __builtin_amdgcn_s_setprio(1);
      MM(a0, b0, 0, 0); MM(a0, b1, 0, 1); MM(a1, b0, 1, 0); MM(a1, b1, 1, 1);
      MM(a2, b0, 2, 0); MM(a2, b1, 2, 1); MM(a3, b0, 3, 0); MM(a3, b1, 3, 1);
      __builtin_amdgcn_s_setprio(0);
    }
    // P1: k-half 1
    {
      bf16x8 a0 = RD_A(rb, 1, 0), a1 = RD_A(rb, 1, 1);
      bf16x8 a2 = RD_A(rb, 1, 2), a3 = RD_A(rb, 1, 3);
      bf16x8 b0 = RD_B(rb, 1, 0), b1 = RD_B(rb, 1, 1);
      ST_A(sb, 1, kn); ST_B(sb, 1, kn);
      __builtin_amdgcn_s_setprio(1);
      MM(a0, b0, 0, 0); MM(a0, b1, 0, 1); MM(a1, b0, 1, 0); MM(a1, b1, 1, 1);
      MM(a2, b0, 2, 0); MM(a2, b1, 2, 1); MM(a3, b0, 3, 0); MM(a3, b1, 3, 1);
      __builtin_amdgcn_s_setprio(0);
    }
    waitv<8>();  // retire tile t+1's 4 loads; t+2,t+3 (8) stay in flight
    barrier_();  // publish + guard LDS reuse of buffer (t+4)&3 == rb
  }
  // epilogue: tiles nt-3, nt-2, nt-1 (resident or draining)
#pragma unroll
  for (int e = 0; e < 3; ++e) {
    const int t = nt - 3 + e, rb = t & 3;
#pragma unroll
    for (int kh = 0; kh < 2; ++kh) {
      bf16x8 a0 = RD_A(rb, kh, 0), a1 = RD_A(rb, kh, 1);
      bf16x8 a2 = RD_A(rb, kh, 2), a3 = RD_A(rb, kh, 3);
      bf16x8 b0 = RD_B(rb, kh, 0), b1 = RD_B(rb, kh, 1);
      __builtin_amdgcn_s_setprio(1);
      MM(a0, b0, 0, 0); MM(a0, b1, 0, 1); MM(a1, b0, 1, 0); MM(a1, b1, 1, 1);
      MM(a2, b0, 2, 0); MM(a2, b1, 2, 1); MM(a3, b0, 3, 0); MM(a3, b1, 3, 1);
      __builtin_amdgcn_s_setprio(0);
    }
    if (e == 0) { waitv<4>(); barrier_(); }
    else if (e == 1) { waitv<0>(); barrier_(); }
  }
#undef RD_A
#undef RD_B
#undef ST_A
#undef ST_B
#undef MM

  const int r0 = brow + wr * 64 + (lane >> 4) * 4;
  const int c0 = bcol + wc * 32 + (lane & 15);
#pragma unroll
  for (int m = 0; m < 4; ++m) {
#pragma unroll
    for (int j = 0; j < 4; ++j) {
      int row = r0 + m * 16 + j;
#pragma unroll
      for (int n = 0; n < 2; ++n) {
        int col = c0 + n * 16;
        float v = acc[m][n][j];
        int64_t idx = (int64_t)row * N + col;
        if (EPI == 1) {
          ((short*)Cp)[idx] = f2b(sigm(v));
        } else if (EPI == 4) {
          float* XC = (float*)Cp;
          XC[idx] = XC[idx] + lif4(v);
        } else if (EPI == 5) {
          float* XC = (float*)Cp;
          float srr = b2f(((const short*)e3)[idx]);
          XC[idx] = XC[idx] + lif4(v * srr);
        }
      }
    }
  }
}

// ---------------- 256x256 4-phase body (shared device function) ---------
// (R17/R18-proven schedule + T5 setprio around MFMA clusters.)
// epi: 0 plain, 1 sigmoid, 2 relu^2 (bf16 out).
__device__ __forceinline__ void g256_body(
    short* lds, const short* __restrict__ A, const short* __restrict__ B,
    short* __restrict__ Cp, int N, int K, int Kst, int brow, int bcol,
    int epi) {
  const int tid = threadIdx.x;
  const short* gA[2];
  const short* gB[2];
  int loff[2];
#pragma unroll
  for (int c = 0; c < 2; ++c) {
    int p = c * 512 + tid;
    int u = p >> 6, s = p & 63;
    gA[c] = A + (int64_t)(brow + u * 16 + (s & 15)) * Kst + (s >> 4) * 8;
    gB[c] = B + (int64_t)(bcol + u * 16 + (s & 15)) * Kst + (s >> 4) * 8;
    loff[c] = p * 8;
  }

  const int lane = tid & 63, wid = tid >> 6;
  const int wr = wid >> 2, wc = wid & 3;

  f32x4 acc[8][4] = {};

#define RD_A(rb, kh, m) \
  (*(const bf16x8*)(lds + (rb) * 32768 + (kh) * 8192 + (wr * 8 + (m)) * 512 + lane * 8))
#define RD_B(rb, kh, n) \
  (*(const bf16x8*)(lds + (rb) * 32768 + 16384 + (kh) * 8192 + (wc * 4 + (n)) * 512 + lane * 8))
#define ST_A(sb, kh, kt)                                                     \
  {                                                                          \
    gload16(gA[0] + (kt) * 64 + (kh) * 32,                                   \
            lds + (sb) * 32768 + (kh) * 8192 + loff[0]);                     \
    gload16(gA[1] + (kt) * 64 + (kh) * 32,                                   \
            lds + (sb) * 32768 + (kh) * 8192 + loff[1]);                     \
  }
#define ST_B(sb, kh, kt)                                                     \
  {                                                                          \
    gload16(gB[0] + (kt) * 64 + (kh) * 32,                                   \
            lds + (sb) * 32768 + 16384 + (kh) * 8192 + loff[0]);             \
    gload16(gB[1] + (kt) * 64 + (kh) * 32,                                   \
            lds + (sb) * 32768 + 16384 + (kh) * 8192 + loff[1]);             \
  }
#define MM(am, bn, i, j) \
  acc[i][j] = __builtin_amdgcn_mfma_f32_16x16x32_bf16(am, bn, acc[i][j], 0, 0, 0)

  const int nt = K / 64;
  ST_A(0, 0, 0); ST_B(0, 0, 0); ST_A(0, 1, 0); ST_B(0, 1, 0);
  waitv<4>();
  barrier_();

  for (int t = 0; t < nt - 1; ++t) {
    const int rb = t & 1, sb = rb ^ 1, kn = t + 1;
    bf16x8 b0, b1, b2, b3;
    {
      bf16x8 a0 = RD_A(rb, 0, 0), a1 = RD_A(rb, 0, 1);
      bf16x8 a2 = RD_A(rb, 0, 2), a3 = RD_A(rb, 0, 3);
      b0 = RD_B(rb, 0, 0); b1 = RD_B(rb, 0, 1);
      b2 = RD_B(rb, 0, 2); b3 = RD_B(rb, 0, 3);
      ST_A(sb, 0, kn);
      __builtin_amdgcn_s_setprio(1);
      MM(a0, b0, 0, 0); MM(a0, b1, 0, 1); MM(a0, b2, 0, 2); MM(a0, b3, 0, 3);
      MM(a1, b0, 1, 0); MM(a1, b1, 1, 1); MM(a1, b2, 1, 2); MM(a1, b3, 1, 3);
      MM(a2, b0, 2, 0); MM(a2, b1, 2, 1); MM(a2, b2, 2, 2); MM(a2, b3, 2, 3);
      MM(a3, b0, 3, 0); MM(a3, b1, 3, 1); MM(a3, b2, 3, 2); MM(a3, b3, 3, 3);
      __builtin_amdgcn_s_setprio(0);
      barrier_();
    }
    {
      bf16x8 a4 = RD_A(rb, 0, 4), a5 = RD_A(rb, 0, 5);
      bf16x8 a6 = RD_A(rb, 0, 6), a7 = RD_A(rb, 0, 7);
      ST_B(sb, 0, kn);
      __builtin_amdgcn_s_setprio(1);
      MM(a4, b0, 4, 0); MM(a4, b1, 4, 1); MM(a4, b2, 4, 2); MM(a4, b3, 4, 3);
      MM(a5, b0, 5, 0); MM(a5, b1, 5, 1); MM(a5, b2, 5, 2); MM(a5, b3, 5, 3);
      MM(a6, b0, 6, 0); MM(a6, b1, 6, 1); MM(a6, b2, 6, 2); MM(a6, b3, 6, 3);
      MM(a7, b0, 7, 0); MM(a7, b1, 7, 1); MM(a7, b2, 7, 2); MM(a7, b3, 7, 3);
      __builtin_amdgcn_s_setprio(0);
      waitv<4>();
      barrier_();
    }
    {
      bf16x8 a0 = RD_A(rb, 1, 0), a1 = RD_A(rb, 1, 1);
      bf16x8 a2 = RD_A(rb, 1, 2), a3 = RD_A(rb, 1, 3);
      b0 = RD_B(rb, 1, 0); b1 = RD_B(rb, 1, 1);
      b2 = RD_B(rb, 1, 2); b3 = RD_B(rb, 1, 3);
      ST_A(sb, 1, kn);
      __builtin_amdgcn_s_setprio(1);
      MM(a0, b0, 0, 0); MM(a0, b1, 0, 1); MM(a0, b2, 0, 2); MM(a0, b3, 0, 3);
      MM(a1, b0, 1, 0); MM(a1, b1, 1, 1); MM(a1, b2, 1, 2); MM(a1, b3, 1, 3);
      MM(a2, b0, 2, 0); MM(a2, b1, 2, 1); MM(a2, b2, 2, 2); MM(a2, b3, 2, 3);
      MM(a3, b0, 3, 0); MM(a3, b1, 3, 1); MM(a3, b2, 3, 2); MM(a3, b3, 3, 3);
      __builtin_amdgcn_s_setprio(0);
      barrier_();
    }
    {
      bf16x8 a4 = RD_A(rb, 1, 4), a5 = RD_A(rb, 1, 5);
      bf16x8 a6 = RD_A(rb, 1, 6), a7 = RD_A(rb, 1, 7);
      ST_B(sb, 1, kn);
      __builtin_amdgcn_s_setprio(1);
      MM(a4, b0, 4, 0); MM(a4, b1, 4, 1); MM(a4, b2, 4, 2); MM(a4, b3, 4, 3);
      MM(a5, b0, 5, 0); MM(a5, b1, 5, 1); MM(a5, b2, 5, 2); MM(a5, b3, 5, 3);
      MM(a6, b0, 6, 0); MM(a6, b1, 6, 1); MM(a6, b2, 6, 2); MM(a6, b3, 6, 3);
      MM(a7, b0, 7, 0); MM(a7, b1, 7, 1); MM(a7, b2, 7, 2); MM(a7, b3, 7, 3);
      __builtin_amdgcn_s_setprio(0);
      waitv<4>();
      barrier_();
    }
  }
  {
    waitv<0>();
    barrier_();
    const int rb = (nt - 1) & 1;
#pragma unroll
    for (int kh = 0; kh < 2; ++kh) {
      bf16x8 b0 = RD_B(rb, kh, 0), b1 = RD_B(rb, kh, 1);
      bf16x8 b2 = RD_B(rb, kh, 2), b3 = RD_B(rb, kh, 3);
#pragma unroll
      for (int m = 0; m < 8; ++m) {
        bf16x8 am = RD_A(rb, kh, m);
        MM(am, b0, m, 0); MM(am, b1, m, 1);
        MM(am, b2, m, 2); MM(am, b3, m, 3);
      }
    }
  }
#undef RD_A
#undef RD_B
#undef ST_A
#undef ST_B
#undef MM

  const int r0 = brow + wr * 128 + (lane >> 4) * 4;
  const int c0 = bcol + wc * 64 + (lane & 15);
#pragma unroll
  for (int m = 0; m < 8; ++m) {
#pragma unroll
    for (int j = 0; j < 4; ++j) {
      int row = r0 + m * 16 + j;
#pragma unroll
      for (int n = 0; n < 4; ++n) {
        int col = c0 + n * 16;
        float v = acc[m][n][j];
        if (epi == 1) v = sigm(v);
        else if (epi == 2) { v = fmaxf(v, 0.0f); v = v * v; }
        Cp[(int64_t)row * N + col] = f2b(v);
      }
    }
  }
}

// tmix wrapper: z-batched 256^2 (grid 4x16x3), epi = (bz==2 ? sigmoid : 0)
__global__ __launch_bounds__(512, 1) void gemm256_z(
    const short* __restrict__ A, const short* __restrict__ B,
    short* __restrict__ C, int64_t sA, int64_t sB, int64_t sC) {
  __shared__ short lds[2 * 32768];
  const unsigned gx = gridDim.x, gy = gridDim.y;
  const unsigned nwg = gx * gy * gridDim.z;
  const unsigned lin = blockIdx.x + gx * (blockIdx.y + gy * blockIdx.z);
  const unsigned cs = nwg >> 3;
  const unsigned nl = (lin & 7) * cs + (lin >> 3);
  const unsigned bxs = nl % gx;
  const unsigned tmp = nl / gx;
  const unsigned bys = tmp % gy;
  const unsigned bz = tmp / gy;
  g256_body(lds, A + bz * sA, B + bz * sB, C + bz * sC, 1024, 1024, 1024,
            bys * 256, bxs * 256, bz == 2 ? 1 : 0);
}

// H wrapper: 256^2 (grid 16x16), relu^2 epilogue.
__global__ __launch_bounds__(512, 1) void gemm256_h(
    const short* __restrict__ A, const short* __restrict__ B,
    short* __restrict__ C) {
  __shared__ short lds[2 * 32768];
  const unsigned gx = gridDim.x, gy = gridDim.y;
  const unsigned nwg = gx * gy;
  const unsigned lin = blockIdx.x + gx * blockIdx.y;
  const unsigned cs = nwg >> 3;
  const unsigned nl = (lin & 7) * cs + (lin >> 3);
  const unsigned bxs = nl % gx;
  const unsigned bys = nl / gx;
  g256_body(lds, A, B, C, 4096, 1024, 1024, bys * 256, bxs * 256, 2);
}

// ---------------- LDS MFMA GEMM (2-barrier path: tails) -----------------
template <int BM, int BN, int EPI, int D, int MINW>
__global__ __launch_bounds__(256, MINW) void gemm_bf16(
    const short* __restrict__ A, const short* __restrict__ B,
    void* __restrict__ Cp, int M, int N, int K, int Kst,
    int64_t sA, int64_t sB, int64_t sC,
    const float* __restrict__ e0, const float* __restrict__ e1,
    const float* __restrict__ e2, const void* __restrict__ e3, int64_t sE) {
  constexpr int MF = BM / 32;
  constexpr int NF = BN / 32;
  constexpr int ASLOT = BM / 64;
  constexpr int BSLOT = BN / 64;
  constexpr int NL = ASLOT + BSLOT;
  constexpr int SBUF = (BM + BN) * 32;
  __shared__ short lds[D * SBUF];
  const int tid = threadIdx.x;

  const unsigned gx = gridDim.x, gy = gridDim.y;
  const unsigned nwg = gx * gy * gridDim.z;
  const unsigned lin = blockIdx.x + gx * (blockIdx.y + gy * blockIdx.z);
  const unsigned cs = nwg >> 3;
  const unsigned nl = (lin & 7) * cs + (lin >> 3);
  const unsigned bxs = nl % gx;
  const unsigned tmp = nl / gx;
  const unsigned bys = tmp % gy;
  const unsigned bz = tmp / gy;

  const int brow = bys * BM;
  const int bcol = bxs * BN;
  const short* Ab = A + bz * sA;
  const short* Bb = B + bz * sB;

  const int srow = ((tid >> 6) << 4) + (tid & 15);
  const int skc = ((tid >> 4) & 3) * 8;
  const short* gA[ASLOT];
  const short* gB[BSLOT];
#pragma unroll
  for (int s = 0; s < ASLOT; ++s)
    gA[s] = Ab + (int64_t)(brow + s * 64 + srow) * Kst + skc;
#pragma unroll
  for (int s = 0; s < BSLOT; ++s)
    gB[s] = Bb + (int64_t)(bcol + s * 64 + srow) * Kst + skc;

  const int lane = tid & 63, wid = tid >> 6;
  const int wr = wid >> 1, wc = wid & 1;

  f32x4 acc[MF][NF] = {};

  auto stage = [&](int buf, int k0) {
    short* d = lds + buf * SBUF;
#pragma unroll
    for (int s = 0; s < ASLOT; ++s)
      gload16(gA[s] + k0, d + s * 2048 + tid * 8);
#pragma unroll
    for (int s = 0; s < BSLOT; ++s)
      gload16(gB[s] + k0, d + BM * 32 + s * 2048 + tid * 8);
  };
  auto compute = [&](int buf) {
    const short* base = lds + buf * SBUF;
    bf16x8 af[MF], bfv[NF];
#pragma unroll
    for (int m = 0; m < MF; ++m)
      af[m] = *(const bf16x8*)(base + (wr * MF + m) * 512 + lane * 8);
#pragma unroll
    for (int n = 0; n < NF; ++n)
      bfv[n] = *(const bf16x8*)(base + BM * 32 + (wc * NF + n) * 512 + lane * 8);
#pragma unroll
    for (int m = 0; m < MF; ++m)
#pragma unroll
      for (int n = 0; n < NF; ++n)
        acc[m][n] = __builtin_amdgcn_mfma_f32_16x16x32_bf16(af[m], bfv[n],
                                                            acc[m][n], 0, 0, 0);
  };

  const int nst = K / 32;
#pragma unroll
  for (int d = 0; d < D - 1; ++d) stage(d, d * 32);
  for (int t = 0; t <= nst - D; ++t) {
    stage((t + D - 1) & (D - 1), (t + D - 1) * 32);
    waitv<(D - 1) * NL>();
    barrier_();
    compute(t & (D - 1));
    barrier_();
  }
  {
    int t = nst - D + 1;
    waitv<0>(); barrier_(); compute(t & (D - 1));
  }

  const int r0 = brow + wr * (BM / 2) + (lane >> 4) * 4;
  const int c0 = bcol + wc * (BN / 2) + (lane & 15);
#pragma unroll
  for (int m = 0; m < MF; ++m) {
#pragma unroll
    for (int j = 0; j < 4; ++j) {
      int row = r0 + m * 16 + j;
#pragma unroll
      for (int n = 0; n < NF; ++n) {
        int col = c0 + n * 16;
        float v = acc[m][n][j];
        int64_t idx = (int64_t)row * N + col;
        if (EPI == 0) {
          ((short*)Cp)[bz * sC + idx] = f2b(v);
        } else if (EPI == 3) {
          float r2 = v + e0[row] * e1[col] + e2[col];
          float xo = ((const float*)e3)[bz * sE + idx];
          ((float*)Cp)[bz * sC + idx] = xo * (1.0f + r2);
        }
      }
    }
  }
}

// ---------------- launch ----------------
extern "C" void kernel_launch(void* const* d_in, const int* in_sizes, int n_in,
                              void* d_out, int out_size, void* d_ws,
                              size_t ws_size, hipStream_t stream) {
  const float* x   = (const float*)d_in[0];
  const float* rt  = (const float*)d_in[1];
  const float* td  = (const float*)d_in[2];
  const float* tf  = (const float*)d_in[3];
  const float* tmk = (const float*)d_in[4];
  const float* tmv = (const float*)d_in[5];
  const float* tmr = (const float*)d_in[6];
  const float* Wk  = (const float*)d_in[7];
  const float* Wv  = (const float*)d_in[8];
  const float* Wr  = (const float*)d_in[9];
  const float* Wo  = (const float*)d_in[10];
  const float* cmk = (const float*)d_in[11];
  const float* cmr = (const float*)d_in[12];
  const float* Wck = (const float*)d_in[13];
  const float* Wcv = (const float*)d_in[14];
  const float* Wcr = (const float*)d_in[15];
  const float* Wrm = (const float*)d_in[16];
  const float* brm = (const float*)d_in[17];
  const float* Wam = (const float*)d_in[18];
  const float* bam = (const float*)d_in[19];
  float* out = (float*)d_out;

  const size_t MB = 1ull << 20;
  uint8_t* W8 = (uint8_t*)d_ws;
  float* XC     = (float*)(W8);                        // 0-16 residual f32
  short* bWck16 = (short*)(W8 + 16 * MB);              // 16-24
  short* S1     = (short*)(W8 + 24 * MB);              // 24-32 xk / SRY / SRR
  short* S2     = (short*)(W8 + 32 * MB);              // 32-40 xv/xk2/rtok,Mt
  short* S3     = (short*)(W8 + 40 * MB);              // 40-48 xr / xr2
  short* bWcv   = (short*)(W8 + 48 * MB);              // 48-56
  short* bWk    = (short*)(W8 + 56 * MB);              // 56-62
  short* bWo    = (short*)(W8 + 62 * MB);
  short* bWcr   = (short*)(W8 + 64 * MB);
  short* bWrm   = (short*)(W8 + 66 * MB);              // 0.5 MB
  short* bWam   = (short*)(W8 + 66 * MB + 512 * 1024); // 0.5 MB
  short* KK     = (short*)(W8 + 67 * MB);              // 67-75
  short* VV     = (short*)(W8 + 75 * MB);              // 75-83
  short* RR     = (short*)(W8 + 83 * MB);              // 83-91
  float* Ca     = (float*)(W8 + 91 * MB);              // wkv temps 91-97
  float* Da     = (float*)(W8 + 92 * MB);
  float* Qa     = (float*)(W8 + 93 * MB);
  float* Aa     = (float*)(W8 + 94 * MB);
  float* Ba     = (float*)(W8 + 95 * MB);
  float* Pa     = (float*)(W8 + 96 * MB);
  short* SRY    = S1;
  short* xk2    = S2;
  short* xr2    = S3;
  short* SRR    = S1;
  short* H16    = KK;                                  // 67-99 (32 MB)
  short* rtok   = S2;                                  // 32-36 (tail)
  short* Mt     = (short*)(W8 + 36 * MB);              // 36-37 (tail)
  float* Sb     = (float*)(W8 + 99 * MB);              // 4 KB

  dim3 blk(256);
  dim3 blk512(512);

  // 0) ALL weight conversions (incl. Wck) + Wam row-sum in one launch
  cvt_all<<<7168, blk, 0, stream>>>(Wk, Wv, Wr, Wo, Wcr, Wcv, Wrm, Wam, Wck,
                                    bWk, bWk + 1048576, bWk + 2097152, bWo,
                                    bWcr, bWcv, bWrm, bWam, bWck16, Sb);

  // 1) FUSED concat + ln1 + time-mix blends -> XC, S1, S2, S3
  ln_mix3<<<TB_ * TT_, blk, 0, stream>>>(x, rt, tmk, tmv, tmr, XC, S1, S2, S3);

  // 2) fused z=3 time-mix: KK/VV/RR   (256^2 4-phase, grid 192, z-batched)
  gemm256_z<<<dim3(4, 16, 3), blk512, 0, stream>>>(
      S1, bWk, KK, 4194304, 1048576, 4194304);
  // 3) wkv chunked scan -> SRY (=S1)
  wkv_p1<<<WKV_NCH * TB_ * 4, blk, 0, stream>>>(td, KK, VV, Ca, Da, Qa);
  wkv_p2<<<32, blk, 0, stream>>>(td, Ca, Da, Qa, Aa, Ba, Pa);
  wkv_p3<<<WKV_NCH * TB_ * 4, blk, 0, stream>>>(td, tf, KK, VV, RR, SRY,
                                                Aa, Ba, Pa);
  // 4) att: XC += lif(SRY*Wo^T)   (2-phase 4-deep ring + setprio)
  gemm2p<4><<<dim3(8, 32), blk512, 0, stream>>>(
      SRY, bWo, XC, 4096, 1024, 1024, 1024, nullptr);
  // 5) fused ln2+mix2 -> xk2(S2), xr2(S3)
  ln_mix2<<<TB_ * TT_, blk, 0, stream>>>(XC, cmk, cmr, xk2, xr2);
  // 6) SRR = sigm(xr2*Wcr^T) -> S1   (2-phase 4-deep + setprio)
  gemm2p<1><<<dim3(8, 32), blk512, 0, stream>>>(
      xr2, bWcr, SRR, 4096, 1024, 1024, 1024, nullptr);
  // 7) H = relu^2(xk2*Wck^T) -> H16   (256^2 4-phase + setprio)
  gemm256_h<<<dim3(16, 16), blk512, 0, stream>>>(xk2, bWck16, H16);
  // 8) XC += lif(SRR*(H*Wcv^T))   (2-phase 4-deep + setprio, K=4096)
  gemm2p<5><<<dim3(8, 32), blk512, 0, stream>>>(
      H16, bWcv, XC, 4096, 1024, 4096, 4096, SRR);
  // 9) tail
  cvt_rtok<<<1024, blk, 0, stream>>>(XC, rtok);
  gemm_bf16<64, 64, 0, 2, 2><<<dim3(4, 4, 8), blk, 0, stream>>>(
      bWrm, rtok, Mt, 256, 256, 1024, 1024, 0, (int64_t)256 * 1024,
      (int64_t)256 * 256, nullptr, nullptr, nullptr, nullptr, 0);
  gemm_bf16<64, 64, 3, 2, 2><<<dim3(16, 4, 8), blk, 0, stream>>>(
      Mt, bWam, out, 256, 1024, 256, 256, (int64_t)256 * 256, 0,
      (int64_t)256 * 1024, brm, Sb, bam, XC, (int64_t)512 * 1024);
}